// Round 1
// baseline (200.128 us; speedup 1.0000x reference)
//
#include <hip/hip_runtime.h>
#include <math.h>

#define NPIX 8192
#define DD 512
#define FF 32
#define NN 16384
#define HWS 1024

// ws layout (bytes)
#define WS_KEYS   0         // 8192 * 8
#define WS_COUNTS 65536     // 16384 * 4
#define WS_LOSSP  131072    // 32 * 4
#define WS_PERPP  131584    // 64 * 4
#define WS_PWT    132096    // 16384 * 4
#define WS_X      197632    // 8192*32*4 = 1 MB
#define WS_EN     1246208   // 16384*32*4 = 2 MB
#define WS_PART   3343360   // 8*8192*32*4 = 8 MB

__global__ __launch_bounds__(256) void transpose_pw(const float* __restrict__ pw, float* __restrict__ pwT) {
    int i = blockIdx.x * 256 + threadIdx.x;       // i over [32][512] row-major
    int f = i >> 9, d = i & 511;
    pwT[d * FF + f] = pw[i];
}

__global__ __launch_bounds__(256) void enorm_k(const float* __restrict__ emb, float* __restrict__ EN) {
    int i = blockIdx.x * 256 + threadIdx.x;       // codebook row
    const float4* r = (const float4*)(emb + (size_t)i * FF);
    float4 v[8];
    float s = 0.f;
#pragma unroll
    for (int q = 0; q < 8; q++) {
        v[q] = r[q];
        s += v[q].x * v[q].x + v[q].y * v[q].y + v[q].z * v[q].z + v[q].w * v[q].w;
    }
    float m = fmaxf(sqrtf(s), 1e-6f);
    float4* o = (float4*)(EN + (size_t)i * FF);
#pragma unroll
    for (int q = 0; q < 8; q++)
        o[q] = make_float4(v[q].x / m, v[q].y / m, v[q].z / m, v[q].w / m);
}

// Partial projection: block (pb, ds) computes sum over d in [ds*64, ds*64+64) for 256 pixels.
__global__ __launch_bounds__(256) void proj_partial(const float* __restrict__ enc, const float* __restrict__ pwT,
                                                    float* __restrict__ part) {
    __shared__ float lds[64 * FF];
    int pb = blockIdx.x;          // 0..31
    int ds = blockIdx.y;          // 0..7
    int d0 = ds * 64;
    for (int i = threadIdx.x; i < 64 * FF; i += 256) lds[i] = pwT[d0 * FF + i];
    __syncthreads();
    int p = pb * 256 + threadIdx.x;
    int b = p >> 10, hw = p & 1023;
    const float* ep = enc + (size_t)b * DD * HWS + hw;
    float acc[FF];
#pragma unroll
    for (int f = 0; f < FF; f++) acc[f] = 0.f;
    for (int dl = 0; dl < 64; dl++) {
        float ev = ep[(size_t)(d0 + dl) * HWS];
        const float4* w4 = (const float4*)&lds[dl * FF];
#pragma unroll
        for (int q = 0; q < 8; q++) {
            float4 w = w4[q];
            acc[q * 4 + 0] = fmaf(ev, w.x, acc[q * 4 + 0]);
            acc[q * 4 + 1] = fmaf(ev, w.y, acc[q * 4 + 1]);
            acc[q * 4 + 2] = fmaf(ev, w.z, acc[q * 4 + 2]);
            acc[q * 4 + 3] = fmaf(ev, w.w, acc[q * 4 + 3]);
        }
    }
    float4* o = (float4*)(part + ((size_t)ds * NPIX + p) * FF);
#pragma unroll
    for (int q = 0; q < 8; q++)
        o[q] = make_float4(acc[q * 4], acc[q * 4 + 1], acc[q * 4 + 2], acc[q * 4 + 3]);
}

__global__ __launch_bounds__(256) void finish_x(const float* __restrict__ part, const float* __restrict__ pbias,
                                                float* __restrict__ X) {
    int p = blockIdx.x * 256 + threadIdx.x;
    float acc[FF];
#pragma unroll
    for (int f = 0; f < FF; f++) acc[f] = 0.f;
    for (int sg = 0; sg < 8; sg++) {
        const float4* r = (const float4*)(part + ((size_t)sg * NPIX + p) * FF);
#pragma unroll
        for (int q = 0; q < 8; q++) {
            float4 v = r[q];
            acc[q * 4 + 0] += v.x; acc[q * 4 + 1] += v.y;
            acc[q * 4 + 2] += v.z; acc[q * 4 + 3] += v.w;
        }
    }
#pragma unroll
    for (int f = 0; f < FF; f++) acc[f] += pbias[f];
    float s = 0.f;
#pragma unroll
    for (int f = 0; f < FF; f++) s += acc[f] * acc[f];
    float m = fmaxf(sqrtf(s), 1e-6f);
    float4* o = (float4*)(X + (size_t)p * FF);
#pragma unroll
    for (int q = 0; q < 8; q++)
        o[q] = make_float4(acc[q * 4] / m, acc[q * 4 + 1] / m, acc[q * 4 + 2] / m, acc[q * 4 + 3] / m);
}

// Fused sims + argmax. grid (32 pixel-blocks, 32 code-splits). thread = pixel.
// Codebook rows are wave-uniform addresses -> broadcast loads from L2.
__global__ __launch_bounds__(256) void argmax_sims(const float* __restrict__ X, const float* __restrict__ EN,
                                                   unsigned long long* __restrict__ keys) {
    int p = blockIdx.x * 256 + threadIdx.x;
    int c0 = blockIdx.y * (NN / 32);   // 512 codes per block
    float x[FF];
    {
        const float4* x4 = (const float4*)(X + (size_t)p * FF);
#pragma unroll
        for (int q = 0; q < 8; q++) {
            float4 v = x4[q];
            x[q * 4] = v.x; x[q * 4 + 1] = v.y; x[q * 4 + 2] = v.z; x[q * 4 + 3] = v.w;
        }
    }
    float best = -2.0f;
    int bestn = c0;
    const float4* e4 = (const float4*)(EN + (size_t)c0 * FF);
#pragma unroll 2
    for (int c = 0; c < NN / 32; c++) {
        float4 e0 = e4[c * 8 + 0], e1 = e4[c * 8 + 1], e2 = e4[c * 8 + 2], e3 = e4[c * 8 + 3];
        float4 e5 = e4[c * 8 + 4], e6 = e4[c * 8 + 5], e7 = e4[c * 8 + 6], e8 = e4[c * 8 + 7];
        float a0 = x[0] * e0.x, a1 = x[1] * e0.y, a2 = x[2] * e0.z, a3 = x[3] * e0.w;
        a0 = fmaf(x[4],  e1.x, a0); a1 = fmaf(x[5],  e1.y, a1); a2 = fmaf(x[6],  e1.z, a2); a3 = fmaf(x[7],  e1.w, a3);
        a0 = fmaf(x[8],  e2.x, a0); a1 = fmaf(x[9],  e2.y, a1); a2 = fmaf(x[10], e2.z, a2); a3 = fmaf(x[11], e2.w, a3);
        a0 = fmaf(x[12], e3.x, a0); a1 = fmaf(x[13], e3.y, a1); a2 = fmaf(x[14], e3.z, a2); a3 = fmaf(x[15], e3.w, a3);
        a0 = fmaf(x[16], e5.x, a0); a1 = fmaf(x[17], e5.y, a1); a2 = fmaf(x[18], e5.z, a2); a3 = fmaf(x[19], e5.w, a3);
        a0 = fmaf(x[20], e6.x, a0); a1 = fmaf(x[21], e6.y, a1); a2 = fmaf(x[22], e6.z, a2); a3 = fmaf(x[23], e6.w, a3);
        a0 = fmaf(x[24], e7.x, a0); a1 = fmaf(x[25], e7.y, a1); a2 = fmaf(x[26], e7.z, a2); a3 = fmaf(x[27], e7.w, a3);
        a0 = fmaf(x[28], e8.x, a0); a1 = fmaf(x[29], e8.y, a1); a2 = fmaf(x[30], e8.z, a2); a3 = fmaf(x[31], e8.w, a3);
        float sim = (a0 + a1) + (a2 + a3);
        if (sim > best) { best = sim; bestn = c0 + c; }   // strict > => first occurrence
    }
    unsigned u = __float_as_uint(best);
    u = (u & 0x80000000u) ? ~u : (u | 0x80000000u);      // monotonic float->uint
    unsigned long long key = ((unsigned long long)u << 32) | (unsigned long long)(~(unsigned)bestn);
    atomicMax(keys + p, key);                             // ties -> smaller n wins
}

__global__ __launch_bounds__(256) void closest_loss_hist(const unsigned long long* __restrict__ keys,
                                                         const float* __restrict__ X, const float* __restrict__ EN,
                                                         float* __restrict__ closest_out, int* __restrict__ counts,
                                                         float* __restrict__ lossp) {
    __shared__ float red[4];
    int p = blockIdx.x * 256 + threadIdx.x;
    unsigned n = ~(unsigned)(keys[p]);
    closest_out[p] = (float)n;
    atomicAdd(counts + n, 1);
    const float4* x4 = (const float4*)(X + (size_t)p * FF);
    const float4* l4 = (const float4*)(EN + (size_t)n * FF);
    float s = 0.f;
#pragma unroll
    for (int q = 0; q < 8; q++) {
        float4 xv = x4[q], lv = l4[q];
        float dx = xv.x - lv.x, dy = xv.y - lv.y, dz = xv.z - lv.z, dw = xv.w - lv.w;
        s += dx * dx + dy * dy + dz * dz + dw * dw;
    }
    for (int off = 32; off > 0; off >>= 1) s += __shfl_down(s, off);
    if ((threadIdx.x & 63) == 0) red[threadIdx.x >> 6] = s;
    __syncthreads();
    if (threadIdx.x == 0) lossp[blockIdx.x] = red[0] + red[1] + red[2] + red[3];
}

// out[b,d,hw] = sum_f lat[f]*exp_w[d,f] + exp_b[d]; lanes = pixels, waves = d-groups.
__global__ __launch_bounds__(256) void expand_out(const unsigned long long* __restrict__ keys,
                                                  const float* __restrict__ EN, const float* __restrict__ ew,
                                                  const float* __restrict__ eb, float* __restrict__ out) {
    int lane = threadIdx.x & 63, wv = threadIdx.x >> 6;
    int p = blockIdx.x * 64 + lane;
    unsigned n = ~(unsigned)(keys[p]);
    float lat[FF];
    const float4* l4 = (const float4*)(EN + (size_t)n * FF);
#pragma unroll
    for (int q = 0; q < 8; q++) {
        float4 v = l4[q];
        lat[q * 4] = v.x; lat[q * 4 + 1] = v.y; lat[q * 4 + 2] = v.z; lat[q * 4 + 3] = v.w;
    }
    int b = p >> 10, hw = p & 1023;
    float* op = out + (size_t)b * DD * HWS + hw;
    int d0 = blockIdx.y * 64 + wv * 16;
    for (int i = 0; i < 16; i++) {
        int d = d0 + i;
        const float4* w4 = (const float4*)(ew + (size_t)d * FF);
        float4 w0 = w4[0], w1 = w4[1], w2 = w4[2], w3 = w4[3];
        float4 w5 = w4[4], w6 = w4[5], w7 = w4[6], w8 = w4[7];
        float a0 = fmaf(lat[0], w0.x, eb[d]);
        float a1 = lat[1] * w0.y;
        float a2 = lat[2] * w0.z;
        float a3 = lat[3] * w0.w;
        a0 = fmaf(lat[4],  w1.x, a0); a1 = fmaf(lat[5],  w1.y, a1); a2 = fmaf(lat[6],  w1.z, a2); a3 = fmaf(lat[7],  w1.w, a3);
        a0 = fmaf(lat[8],  w2.x, a0); a1 = fmaf(lat[9],  w2.y, a1); a2 = fmaf(lat[10], w2.z, a2); a3 = fmaf(lat[11], w2.w, a3);
        a0 = fmaf(lat[12], w3.x, a0); a1 = fmaf(lat[13], w3.y, a1); a2 = fmaf(lat[14], w3.z, a2); a3 = fmaf(lat[15], w3.w, a3);
        a0 = fmaf(lat[16], w5.x, a0); a1 = fmaf(lat[17], w5.y, a1); a2 = fmaf(lat[18], w5.z, a2); a3 = fmaf(lat[19], w5.w, a3);
        a0 = fmaf(lat[20], w6.x, a0); a1 = fmaf(lat[21], w6.y, a1); a2 = fmaf(lat[22], w6.z, a2); a3 = fmaf(lat[23], w6.w, a3);
        a0 = fmaf(lat[24], w7.x, a0); a1 = fmaf(lat[25], w7.y, a1); a2 = fmaf(lat[26], w7.z, a2); a3 = fmaf(lat[27], w7.w, a3);
        a0 = fmaf(lat[28], w8.x, a0); a1 = fmaf(lat[29], w8.y, a1); a2 = fmaf(lat[30], w8.z, a2); a3 = fmaf(lat[31], w8.w, a3);
        op[(size_t)d * HWS] = (a0 + a1) + (a2 + a3);
    }
}

__global__ __launch_bounds__(256) void perp_partial(const int* __restrict__ counts, float* __restrict__ perpp) {
    __shared__ float red[4];
    int i = blockIdx.x * 256 + threadIdx.x;
    float u = (float)counts[i] * (1.0f / 8192.0f);
    float s = u * logf(u + 1e-6f);
    for (int off = 32; off > 0; off >>= 1) s += __shfl_down(s, off);
    if ((threadIdx.x & 63) == 0) red[threadIdx.x >> 6] = s;
    __syncthreads();
    if (threadIdx.x == 0) perpp[blockIdx.x] = red[0] + red[1] + red[2] + red[3];
}

__global__ void finalize(const float* __restrict__ lossp, const float* __restrict__ perpp, float* __restrict__ o) {
    if (threadIdx.x == 0) {
        float l = 0.f;
        for (int i = 0; i < 32; i++) l += lossp[i];
        float s = 0.f;
        for (int i = 0; i < 64; i++) s += perpp[i];
        o[0] = l * (1.0f / 262144.0f);   // mean over B*F*H*W = 262144
        o[1] = expf(-s);
    }
}

extern "C" void kernel_launch(void* const* d_in, const int* in_sizes, int n_in,
                              void* d_out, int out_size, void* d_ws, size_t ws_size,
                              hipStream_t stream) {
    const float* enc = (const float*)d_in[0];
    const float* emb = (const float*)d_in[1];
    const float* pw  = (const float*)d_in[2];
    const float* pb  = (const float*)d_in[3];
    const float* ew  = (const float*)d_in[4];
    const float* eb  = (const float*)d_in[5];
    float* out = (float*)d_out;
    char* ws = (char*)d_ws;

    unsigned long long* keys = (unsigned long long*)(ws + WS_KEYS);
    int*   counts = (int*)(ws + WS_COUNTS);
    float* lossp  = (float*)(ws + WS_LOSSP);
    float* perpp  = (float*)(ws + WS_PERPP);
    float* pwT    = (float*)(ws + WS_PWT);
    float* X      = (float*)(ws + WS_X);
    float* EN     = (float*)(ws + WS_EN);
    float* part   = (float*)(ws + WS_PART);

    hipMemsetAsync(ws, 0, WS_PWT, stream);   // zero keys + counts + partials

    transpose_pw<<<64, 256, 0, stream>>>(pw, pwT);
    enorm_k<<<64, 256, 0, stream>>>(emb, EN);
    proj_partial<<<dim3(32, 8), 256, 0, stream>>>(enc, pwT, part);
    finish_x<<<32, 256, 0, stream>>>(part, pb, X);
    argmax_sims<<<dim3(32, 32), 256, 0, stream>>>(X, EN, keys);
    closest_loss_hist<<<32, 256, 0, stream>>>(keys, X, EN, out + 4194304, counts, lossp);
    expand_out<<<dim3(128, 8), 256, 0, stream>>>(keys, EN, ew, eb, out);
    perp_partial<<<64, 256, 0, stream>>>(counts, perpp);
    finalize<<<1, 64, 0, stream>>>(lossp, perpp, out + 4194304 + NPIX);
}

// Round 2
// 133.037 us; speedup vs baseline: 1.5043x; 1.5043x over previous
//
#include <hip/hip_runtime.h>
#include <math.h>

#define NPIX 8192
#define DD 512
#define FF 32
#define NN 16384
#define HWS 1024
#define DSPLIT 4

// ws layout (bytes)
#define WS_KEYS   0         // 8192*8
#define WS_COUNTS 65536     // 16384*4
#define WS_LOSSP  131072    // 32*4
#define WS_PERPP  131584    // 64*4
#define WS_PWT    132096    // 16384*4
#define WS_X      197632    // 8192*32*4 = 1 MB
#define WS_EN     1246208   // 16384*32*4 = 2 MB
#define WS_XH     3343360   // 8192*32*2 = 512 KB
#define WS_XM     3867648
#define WS_XL     4391936
#define WS_EH     4916224   // 16384*32*2 = 1 MB (swizzled chunk-major)
#define WS_EM     5964800
#define WS_EL     7013376
#define WS_PART   8061952   // 4*8192*32*4 = 4 MB  (end 12256256)

typedef __bf16 bf16x8 __attribute__((ext_vector_type(8)));
typedef float f32x4 __attribute__((ext_vector_type(4)));
typedef unsigned int uint32x4 __attribute__((ext_vector_type(4)));

__device__ __forceinline__ unsigned short bf16_rne(float f) {
    unsigned u = __float_as_uint(f);
    u += 0x7fffu + ((u >> 16) & 1u);
    return (unsigned short)(u >> 16);
}
__device__ __forceinline__ float bf16_to_f(unsigned short h) {
    return __uint_as_float(((unsigned)h) << 16);
}
// byte offset of code c (0..127), k-group kg (0..3) within one 8 KB chunk, bank-swizzled
__device__ __forceinline__ int swz_off(int c, int kg) {
    return (c * 64 + kg * 16) ^ ((c & 7) << 4);
}
__device__ __forceinline__ f32x4 mfma16(bf16x8 a, bf16x8 b, f32x4 c) {
    return __builtin_amdgcn_mfma_f32_16x16x32_bf16(a, b, c, 0, 0, 0);
}
__device__ __forceinline__ void gl_lds16(const void* g, void* l) {
    __builtin_amdgcn_global_load_lds((const __attribute__((address_space(1))) unsigned int*)g,
                                     (__attribute__((address_space(3))) unsigned int*)l, 16, 0, 0);
}
__device__ __forceinline__ unsigned long long packkey(float v, int n) {
    unsigned u = __float_as_uint(v);
    u = (u & 0x80000000u) ? ~u : (u | 0x80000000u);   // monotonic float->uint
    return ((unsigned long long)u << 32) | (unsigned long long)(~(unsigned)n);
}

__global__ __launch_bounds__(256) void transpose_pw(const float* __restrict__ pw, float* __restrict__ pwT) {
    int i = blockIdx.x * 256 + threadIdx.x;       // i over [32][512] row-major
    int f = i >> 9, d = i & 511;
    pwT[d * FF + f] = pw[i];
}

// l2-normalize codebook; emit fp32 EN + 3-way bf16 splits in swizzled chunk-major layout
__global__ __launch_bounds__(256) void enorm_k(const float* __restrict__ emb, float* __restrict__ EN,
                                               char* __restrict__ EH, char* __restrict__ EM, char* __restrict__ EL) {
    int n = blockIdx.x * 256 + threadIdx.x;
    const float4* r = (const float4*)(emb + (size_t)n * FF);
    float e[FF];
    float s = 0.f;
#pragma unroll
    for (int q = 0; q < 8; q++) {
        float4 v = r[q];
        e[q * 4] = v.x; e[q * 4 + 1] = v.y; e[q * 4 + 2] = v.z; e[q * 4 + 3] = v.w;
        s += v.x * v.x + v.y * v.y + v.z * v.z + v.w * v.w;
    }
    float m = fmaxf(sqrtf(s), 1e-6f);
#pragma unroll
    for (int f = 0; f < FF; f++) e[f] = e[f] / m;
    float4* o = (float4*)(EN + (size_t)n * FF);
#pragma unroll
    for (int q = 0; q < 8; q++)
        o[q] = make_float4(e[q * 4], e[q * 4 + 1], e[q * 4 + 2], e[q * 4 + 3]);

    int chunk = n >> 7, c = n & 127;
    size_t cb = (size_t)chunk * 8192;
#pragma unroll
    for (int kg = 0; kg < 4; kg++) {
        unsigned hw_[4], mw_[4], lw_[4];
#pragma unroll
        for (int w = 0; w < 4; w++) {
            unsigned short hh[2], mm2[2], ll[2];
#pragma unroll
            for (int b = 0; b < 2; b++) {
                float f0 = e[kg * 8 + w * 2 + b];
                unsigned short h = bf16_rne(f0);
                float r1 = f0 - bf16_to_f(h);
                unsigned short mmv = bf16_rne(r1);
                float r2 = r1 - bf16_to_f(mmv);
                unsigned short lv = bf16_rne(r2);
                hh[b] = h; mm2[b] = mmv; ll[b] = lv;
            }
            hw_[w] = (unsigned)hh[0] | ((unsigned)hh[1] << 16);
            mw_[w] = (unsigned)mm2[0] | ((unsigned)mm2[1] << 16);
            lw_[w] = (unsigned)ll[0] | ((unsigned)ll[1] << 16);
        }
        int off = swz_off(c, kg);
        uint32x4 th = {hw_[0], hw_[1], hw_[2], hw_[3]};
        uint32x4 tm = {mw_[0], mw_[1], mw_[2], mw_[3]};
        uint32x4 tl = {lw_[0], lw_[1], lw_[2], lw_[3]};
        *(uint32x4*)(EH + cb + off) = th;
        *(uint32x4*)(EM + cb + off) = tm;
        *(uint32x4*)(EL + cb + off) = tl;
    }
}

// Partial projection: block (pb, ds) computes sum over d in [ds*128, +128) for 256 pixels.
__global__ __launch_bounds__(256) void proj_partial(const float* __restrict__ enc, const float* __restrict__ pwT,
                                                    float* __restrict__ part) {
    __shared__ float lds[128 * FF];
    int pb = blockIdx.x;          // 0..31
    int ds = blockIdx.y;          // 0..3
    int d0 = ds * 128;
    for (int i = threadIdx.x; i < 128 * FF; i += 256) lds[i] = pwT[d0 * FF + i];
    __syncthreads();
    int p = pb * 256 + threadIdx.x;
    int b = p >> 10, hw = p & 1023;
    const float* ep = enc + (size_t)b * DD * HWS + hw;
    float acc[FF];
#pragma unroll
    for (int f = 0; f < FF; f++) acc[f] = 0.f;
    for (int dl = 0; dl < 128; dl++) {
        float ev = ep[(size_t)(d0 + dl) * HWS];
        const float4* w4 = (const float4*)&lds[dl * FF];
#pragma unroll
        for (int q = 0; q < 8; q++) {
            float4 w = w4[q];
            acc[q * 4 + 0] = fmaf(ev, w.x, acc[q * 4 + 0]);
            acc[q * 4 + 1] = fmaf(ev, w.y, acc[q * 4 + 1]);
            acc[q * 4 + 2] = fmaf(ev, w.z, acc[q * 4 + 2]);
            acc[q * 4 + 3] = fmaf(ev, w.w, acc[q * 4 + 3]);
        }
    }
    float4* o = (float4*)(part + ((size_t)ds * NPIX + p) * FF);
#pragma unroll
    for (int q = 0; q < 8; q++)
        o[q] = make_float4(acc[q * 4], acc[q * 4 + 1], acc[q * 4 + 2], acc[q * 4 + 3]);
}

// Sum partials + bias, l2norm -> X fp32, plus 3-way bf16 splits row-major [p][32]
__global__ __launch_bounds__(256) void finish_x(const float* __restrict__ part, const float* __restrict__ pbias,
                                                float* __restrict__ X,
                                                char* __restrict__ XH, char* __restrict__ XM, char* __restrict__ XL) {
    int p = blockIdx.x * 256 + threadIdx.x;
    float acc[FF];
#pragma unroll
    for (int f = 0; f < FF; f++) acc[f] = 0.f;
    for (int sg = 0; sg < DSPLIT; sg++) {
        const float4* r = (const float4*)(part + ((size_t)sg * NPIX + p) * FF);
#pragma unroll
        for (int q = 0; q < 8; q++) {
            float4 v = r[q];
            acc[q * 4 + 0] += v.x; acc[q * 4 + 1] += v.y;
            acc[q * 4 + 2] += v.z; acc[q * 4 + 3] += v.w;
        }
    }
#pragma unroll
    for (int f = 0; f < FF; f++) acc[f] += pbias[f];
    float s = 0.f;
#pragma unroll
    for (int f = 0; f < FF; f++) s += acc[f] * acc[f];
    float m = fmaxf(sqrtf(s), 1e-6f);
#pragma unroll
    for (int f = 0; f < FF; f++) acc[f] = acc[f] / m;
    float4* o = (float4*)(X + (size_t)p * FF);
#pragma unroll
    for (int q = 0; q < 8; q++)
        o[q] = make_float4(acc[q * 4], acc[q * 4 + 1], acc[q * 4 + 2], acc[q * 4 + 3]);

    size_t pb64 = (size_t)p * 64;
#pragma unroll
    for (int kg = 0; kg < 4; kg++) {
        unsigned hw_[4], mw_[4], lw_[4];
#pragma unroll
        for (int w = 0; w < 4; w++) {
            unsigned short hh[2], mm2[2], ll[2];
#pragma unroll
            for (int b = 0; b < 2; b++) {
                float f0 = acc[kg * 8 + w * 2 + b];
                unsigned short h = bf16_rne(f0);
                float r1 = f0 - bf16_to_f(h);
                unsigned short mmv = bf16_rne(r1);
                float r2 = r1 - bf16_to_f(mmv);
                unsigned short lv = bf16_rne(r2);
                hh[b] = h; mm2[b] = mmv; ll[b] = lv;
            }
            hw_[w] = (unsigned)hh[0] | ((unsigned)hh[1] << 16);
            mw_[w] = (unsigned)mm2[0] | ((unsigned)mm2[1] << 16);
            lw_[w] = (unsigned)ll[0] | ((unsigned)ll[1] << 16);
        }
        uint32x4 th = {hw_[0], hw_[1], hw_[2], hw_[3]};
        uint32x4 tm = {mw_[0], mw_[1], mw_[2], mw_[3]};
        uint32x4 tl = {lw_[0], lw_[1], lw_[2], lw_[3]};
        *(uint32x4*)(XH + pb64 + kg * 16) = th;
        *(uint32x4*)(XM + pb64 + kg * 16) = tm;
        *(uint32x4*)(XL + pb64 + kg * 16) = tl;
    }
}

// Fused MFMA sims+argmax. grid (32 m-blocks, 16 n-chunks), 512 threads (8 waves).
// Wave owns 32 pixels (two 16-row A tiles). Per n-chunk block: 1024 codes in 8
// LDS chunks of 128 codes, double-buffered via global_load_lds from pre-swizzled
// global splits. 6 mfma terms (h/m/l split) per 16x16 tile, fp32 accumulate.
__global__ __launch_bounds__(512) void argmax_mfma(const uint32x4* __restrict__ XHp, const uint32x4* __restrict__ XMp,
                                                   const uint32x4* __restrict__ XLp,
                                                   const char* __restrict__ EH, const char* __restrict__ EM,
                                                   const char* __restrict__ EL,
                                                   unsigned long long* __restrict__ keys) {
    __shared__ char lds[2][3][8192];
    int tid = threadIdx.x;
    int lane = tid & 63, wv = tid >> 6;
    int mblk = blockIdx.x, nblk = blockIdx.y;
    int rl = lane & 15, kg = lane >> 4;
    int pbase = mblk * 256 + wv * 32;
    int p0 = pbase + rl, p1 = p0 + 16;

    bf16x8 a0h = __builtin_bit_cast(bf16x8, XHp[p0 * 4 + kg]);
    bf16x8 a0m = __builtin_bit_cast(bf16x8, XMp[p0 * 4 + kg]);
    bf16x8 a0l = __builtin_bit_cast(bf16x8, XLp[p0 * 4 + kg]);
    bf16x8 a1h = __builtin_bit_cast(bf16x8, XHp[p1 * 4 + kg]);
    bf16x8 a1m = __builtin_bit_cast(bf16x8, XMp[p1 * 4 + kg]);
    bf16x8 a1l = __builtin_bit_cast(bf16x8, XLp[p1 * 4 + kg]);

    int off0 = (rl * 64 + kg * 16) ^ ((rl & 7) << 4);   // swizzled ds_read offset (per-lane const)
    int lo = wv * 1024;                                  // wave-uniform LDS dst
    size_t go = (size_t)tid * 16;                        // per-lane global src

    float bv0[4], bv1[4]; int bn0[4], bn1[4];
#pragma unroll
    for (int i = 0; i < 4; i++) { bv0[i] = -3.0e38f; bv1[i] = -3.0e38f; bn0[i] = 0; bn1[i] = 0; }
    int ntl = nblk * 1024 + rl;

    // stage chunk 0 into buffer 0
    {
        size_t gb = ((size_t)(nblk * 8 + 0)) * 8192 + go;
        gl_lds16(EH + gb, &lds[0][0][lo]);
        gl_lds16(EM + gb, &lds[0][1][lo]);
        gl_lds16(EL + gb, &lds[0][2][lo]);
    }
    __syncthreads();

    for (int ci = 0; ci < 8; ci++) {
        int buf = ci & 1;
        if (ci < 7) {
            size_t gb = ((size_t)(nblk * 8 + ci + 1)) * 8192 + go;
            gl_lds16(EH + gb, &lds[buf ^ 1][0][lo]);
            gl_lds16(EM + gb, &lds[buf ^ 1][1][lo]);
            gl_lds16(EL + gb, &lds[buf ^ 1][2][lo]);
        }
        const char* bhB = &lds[buf][0][0];
        const char* bmB = &lds[buf][1][0];
        const char* blB = &lds[buf][2][0];
        for (int t = 0; t < 8; t++) {
            int o = t * 1024 + off0;
            bf16x8 bh = __builtin_bit_cast(bf16x8, *(const uint32x4*)(bhB + o));
            bf16x8 bm = __builtin_bit_cast(bf16x8, *(const uint32x4*)(bmB + o));
            bf16x8 bl = __builtin_bit_cast(bf16x8, *(const uint32x4*)(blB + o));
            f32x4 acc0 = {0.f, 0.f, 0.f, 0.f};
            f32x4 acc1 = {0.f, 0.f, 0.f, 0.f};
            acc0 = mfma16(a0h, bh, acc0);
            acc1 = mfma16(a1h, bh, acc1);
            acc0 = mfma16(a0h, bm, acc0);
            acc1 = mfma16(a1h, bm, acc1);
            acc0 = mfma16(a0m, bh, acc0);
            acc1 = mfma16(a1m, bh, acc1);
            acc0 = mfma16(a0m, bm, acc0);
            acc1 = mfma16(a1m, bm, acc1);
            acc0 = mfma16(a0h, bl, acc0);
            acc1 = mfma16(a1h, bl, acc1);
            acc0 = mfma16(a0l, bh, acc0);
            acc1 = mfma16(a1l, bh, acc1);
            int n = ntl + ci * 128 + t * 16;
#pragma unroll
            for (int i = 0; i < 4; i++) {
                if (acc0[i] > bv0[i]) { bv0[i] = acc0[i]; bn0[i] = n; }
                if (acc1[i] > bv1[i]) { bv1[i] = acc1[i]; bn1[i] = n; }
            }
        }
        __syncthreads();
    }

    // reduce over the 16 code-columns within each 16-lane group (ties -> smaller n)
#pragma unroll
    for (int st = 1; st < 16; st <<= 1) {
#pragma unroll
        for (int i = 0; i < 4; i++) {
            float v = __shfl_xor(bv0[i], st); int nn = __shfl_xor(bn0[i], st);
            if (v > bv0[i] || (v == bv0[i] && nn < bn0[i])) { bv0[i] = v; bn0[i] = nn; }
            v = __shfl_xor(bv1[i], st); nn = __shfl_xor(bn1[i], st);
            if (v > bv1[i] || (v == bv1[i] && nn < bn1[i])) { bv1[i] = v; bn1[i] = nn; }
        }
    }
    if (rl == 0) {
#pragma unroll
        for (int i = 0; i < 4; i++) {
            atomicMax(keys + pbase + kg * 4 + i, packkey(bv0[i], bn0[i]));
            atomicMax(keys + pbase + 16 + kg * 4 + i, packkey(bv1[i], bn1[i]));
        }
    }
}

__global__ __launch_bounds__(256) void closest_loss_hist(const unsigned long long* __restrict__ keys,
                                                         const float* __restrict__ X, const float* __restrict__ EN,
                                                         float* __restrict__ closest_out, int* __restrict__ counts,
                                                         float* __restrict__ lossp) {
    __shared__ float red[4];
    int p = blockIdx.x * 256 + threadIdx.x;
    unsigned n = ~(unsigned)(keys[p]);
    closest_out[p] = (float)n;
    atomicAdd(counts + n, 1);
    const float4* x4 = (const float4*)(X + (size_t)p * FF);
    const float4* l4 = (const float4*)(EN + (size_t)n * FF);
    float s = 0.f;
#pragma unroll
    for (int q = 0; q < 8; q++) {
        float4 xv = x4[q], lv = l4[q];
        float dx = xv.x - lv.x, dy = xv.y - lv.y, dz = xv.z - lv.z, dw = xv.w - lv.w;
        s += dx * dx + dy * dy + dz * dz + dw * dw;
    }
    for (int off = 32; off > 0; off >>= 1) s += __shfl_down(s, off);
    if ((threadIdx.x & 63) == 0) red[threadIdx.x >> 6] = s;
    __syncthreads();
    if (threadIdx.x == 0) lossp[blockIdx.x] = red[0] + red[1] + red[2] + red[3];
}

// out[b,d,hw] = sum_f lat[f]*exp_w[d,f] + exp_b[d]; lanes = pixels, waves = d-groups.
__global__ __launch_bounds__(256) void expand_out(const unsigned long long* __restrict__ keys,
                                                  const float* __restrict__ EN, const float* __restrict__ ew,
                                                  const float* __restrict__ eb, float* __restrict__ out) {
    int lane = threadIdx.x & 63, wv = threadIdx.x >> 6;
    int p = blockIdx.x * 64 + lane;
    unsigned n = ~(unsigned)(keys[p]);
    float lat[FF];
    const float4* l4 = (const float4*)(EN + (size_t)n * FF);
#pragma unroll
    for (int q = 0; q < 8; q++) {
        float4 v = l4[q];
        lat[q * 4] = v.x; lat[q * 4 + 1] = v.y; lat[q * 4 + 2] = v.z; lat[q * 4 + 3] = v.w;
    }
    int b = p >> 10, hw = p & 1023;
    float* op = out + (size_t)b * DD * HWS + hw;
    int d0 = blockIdx.y * 64 + wv * 16;
    for (int i = 0; i < 16; i++) {
        int d = d0 + i;
        const float4* w4 = (const float4*)(ew + (size_t)d * FF);
        float4 w0 = w4[0], w1 = w4[1], w2 = w4[2], w3 = w4[3];
        float4 w5 = w4[4], w6 = w4[5], w7 = w4[6], w8 = w4[7];
        float a0 = fmaf(lat[0], w0.x, eb[d]);
        float a1 = lat[1] * w0.y;
        float a2 = lat[2] * w0.z;
        float a3 = lat[3] * w0.w;
        a0 = fmaf(lat[4],  w1.x, a0); a1 = fmaf(lat[5],  w1.y, a1); a2 = fmaf(lat[6],  w1.z, a2); a3 = fmaf(lat[7],  w1.w, a3);
        a0 = fmaf(lat[8],  w2.x, a0); a1 = fmaf(lat[9],  w2.y, a1); a2 = fmaf(lat[10], w2.z, a2); a3 = fmaf(lat[11], w2.w, a3);
        a0 = fmaf(lat[12], w3.x, a0); a1 = fmaf(lat[13], w3.y, a1); a2 = fmaf(lat[14], w3.z, a2); a3 = fmaf(lat[15], w3.w, a3);
        a0 = fmaf(lat[16], w5.x, a0); a1 = fmaf(lat[17], w5.y, a1); a2 = fmaf(lat[18], w5.z, a2); a3 = fmaf(lat[19], w5.w, a3);
        a0 = fmaf(lat[20], w6.x, a0); a1 = fmaf(lat[21], w6.y, a1); a2 = fmaf(lat[22], w6.z, a2); a3 = fmaf(lat[23], w6.w, a3);
        a0 = fmaf(lat[24], w7.x, a0); a1 = fmaf(lat[25], w7.y, a1); a2 = fmaf(lat[26], w7.z, a2); a3 = fmaf(lat[27], w7.w, a3);
        a0 = fmaf(lat[28], w8.x, a0); a1 = fmaf(lat[29], w8.y, a1); a2 = fmaf(lat[30], w8.z, a2); a3 = fmaf(lat[31], w8.w, a3);
        op[(size_t)d * HWS] = (a0 + a1) + (a2 + a3);
    }
}

__global__ __launch_bounds__(256) void perp_partial(const int* __restrict__ counts, float* __restrict__ perpp) {
    __shared__ float red[4];
    int i = blockIdx.x * 256 + threadIdx.x;
    float u = (float)counts[i] * (1.0f / 8192.0f);
    float s = u * logf(u + 1e-6f);
    for (int off = 32; off > 0; off >>= 1) s += __shfl_down(s, off);
    if ((threadIdx.x & 63) == 0) red[threadIdx.x >> 6] = s;
    __syncthreads();
    if (threadIdx.x == 0) perpp[blockIdx.x] = red[0] + red[1] + red[2] + red[3];
}

__global__ void finalize(const float* __restrict__ lossp, const float* __restrict__ perpp, float* __restrict__ o) {
    if (threadIdx.x == 0) {
        float l = 0.f;
        for (int i = 0; i < 32; i++) l += lossp[i];
        float s = 0.f;
        for (int i = 0; i < 64; i++) s += perpp[i];
        o[0] = l * (1.0f / 262144.0f);   // mean over B*F*H*W = 262144
        o[1] = expf(-s);
    }
}

extern "C" void kernel_launch(void* const* d_in, const int* in_sizes, int n_in,
                              void* d_out, int out_size, void* d_ws, size_t ws_size,
                              hipStream_t stream) {
    const float* enc = (const float*)d_in[0];
    const float* emb = (const float*)d_in[1];
    const float* pw  = (const float*)d_in[2];
    const float* pb  = (const float*)d_in[3];
    const float* ew  = (const float*)d_in[4];
    const float* eb  = (const float*)d_in[5];
    float* out = (float*)d_out;
    char* ws = (char*)d_ws;

    unsigned long long* keys = (unsigned long long*)(ws + WS_KEYS);
    int*   counts = (int*)(ws + WS_COUNTS);
    float* lossp  = (float*)(ws + WS_LOSSP);
    float* perpp  = (float*)(ws + WS_PERPP);
    float* pwT    = (float*)(ws + WS_PWT);
    float* X      = (float*)(ws + WS_X);
    float* EN     = (float*)(ws + WS_EN);
    char*  XH     = ws + WS_XH;
    char*  XM     = ws + WS_XM;
    char*  XL     = ws + WS_XL;
    char*  EH     = ws + WS_EH;
    char*  EM     = ws + WS_EM;
    char*  EL     = ws + WS_EL;
    float* part   = (float*)(ws + WS_PART);

    hipMemsetAsync(ws, 0, WS_PWT, stream);   // zero keys + counts + reduction slots

    transpose_pw<<<64, 256, 0, stream>>>(pw, pwT);
    enorm_k<<<64, 256, 0, stream>>>(emb, EN, EH, EM, EL);
    proj_partial<<<dim3(32, DSPLIT), 256, 0, stream>>>(enc, pwT, part);
    finish_x<<<32, 256, 0, stream>>>(part, pb, X, XH, XM, XL);
    argmax_mfma<<<dim3(32, 16), 512, 0, stream>>>((const uint32x4*)XH, (const uint32x4*)XM, (const uint32x4*)XL,
                                                  EH, EM, EL, keys);
    closest_loss_hist<<<32, 256, 0, stream>>>(keys, X, EN, out + 4194304, counts, lossp);
    expand_out<<<dim3(128, 8), 256, 0, stream>>>(keys, EN, ew, eb, out);
    perp_partial<<<64, 256, 0, stream>>>(counts, perpp);
    finalize<<<1, 64, 0, stream>>>(lossp, perpp, out + 4194304 + NPIX);
}

// Round 3
// 116.872 us; speedup vs baseline: 1.7124x; 1.1383x over previous
//
#include <hip/hip_runtime.h>
#include <math.h>

#define NPIX 8192
#define DD 512
#define FF 32
#define NN 16384
#define HWS 1024
#define DSPLIT 4
#define MARGIN 0.012f

// ws layout (bytes)
#define WS_KEYS64 0         // 8192*8  = 65536
#define WS_KEYS32 65536     // 8192*4  = 32768
#define WS_COUNTS 98304     // 16384*4 = 65536
#define WS_MISC   163840    // 256 (loss accumulator)
#define WS_PWT    164096    // 65536
#define WS_EN     229632    // 2 MB
#define WS_EH     2326784   // 1 MB (tile-major bf16 h-split; +4KB overread into WS_X is harmless)
#define WS_X      3375360   // 1 MB
#define WS_XH     4423936   // 512 KB
#define WS_PART   4948224   // 4*8192*32*4 = 4 MB (end 9142528)

typedef __bf16 bf16x8 __attribute__((ext_vector_type(8)));
typedef float f32x4 __attribute__((ext_vector_type(4)));
typedef unsigned int uint32x4 __attribute__((ext_vector_type(4)));

__device__ __forceinline__ unsigned short bf16_rne(float f) {
    unsigned u = __float_as_uint(f);
    u += 0x7fffu + ((u >> 16) & 1u);
    return (unsigned short)(u >> 16);
}
__device__ __forceinline__ f32x4 mfma16(bf16x8 a, bf16x8 b, f32x4 c) {
    return __builtin_amdgcn_mfma_f32_16x16x32_bf16(a, b, c, 0, 0, 0);
}
__device__ __forceinline__ unsigned mono_u32(float v) {
    unsigned u = __float_as_uint(v);
    return (u & 0x80000000u) ? ~u : (u | 0x80000000u);
}
__device__ __forceinline__ float mono_dec(unsigned u) {
    return __uint_as_float((u & 0x80000000u) ? (u ^ 0x80000000u) : ~u);
}
__device__ __forceinline__ unsigned long long packkey(float v, int n) {
    return ((unsigned long long)mono_u32(v) << 32) | (unsigned long long)(~(unsigned)n);
}

// prep: transpose proj_w, l2-normalize codebook (fp32 EN + bf16-h tile-major EH),
// zero keys64/keys32/counts/loss. 16384 threads.
__global__ __launch_bounds__(256) void prep(const float* __restrict__ pw, const float* __restrict__ emb,
                                            float* __restrict__ pwT, float* __restrict__ EN,
                                            char* __restrict__ EH,
                                            unsigned long long* __restrict__ keys64,
                                            unsigned* __restrict__ keys32, int* __restrict__ counts,
                                            float* __restrict__ misc) {
    int i = blockIdx.x * 256 + threadIdx.x;
    pwT[(i & 511) * FF + (i >> 9)] = pw[i];
    counts[i] = 0;
    if (i < 8192) { keys64[i] = 0ull; keys32[i] = 0u; }
    if (i < 8) misc[i] = 0.f;

    // codebook row i
    const float4* r = (const float4*)(emb + (size_t)i * FF);
    float e[FF];
    float s = 0.f;
#pragma unroll
    for (int q = 0; q < 8; q++) {
        float4 v = r[q];
        e[q * 4] = v.x; e[q * 4 + 1] = v.y; e[q * 4 + 2] = v.z; e[q * 4 + 3] = v.w;
        s += v.x * v.x + v.y * v.y + v.z * v.z + v.w * v.w;
    }
    float m = fmaxf(sqrtf(s), 1e-6f);
#pragma unroll
    for (int f = 0; f < FF; f++) e[f] = e[f] / m;
    float4* o = (float4*)(EN + (size_t)i * FF);
#pragma unroll
    for (int q = 0; q < 8; q++)
        o[q] = make_float4(e[q * 4], e[q * 4 + 1], e[q * 4 + 2], e[q * 4 + 3]);

    // EH tile-major: tile g = i>>4 (16 codes), lane piece (kg*16 + rl)*16 bytes
    int g = i >> 4, rl = i & 15;
#pragma unroll
    for (int kg = 0; kg < 4; kg++) {
        unsigned hw_[4];
#pragma unroll
        for (int w = 0; w < 4; w++) {
            unsigned short h0 = bf16_rne(e[kg * 8 + w * 2]);
            unsigned short h1 = bf16_rne(e[kg * 8 + w * 2 + 1]);
            hw_[w] = (unsigned)h0 | ((unsigned)h1 << 16);
        }
        uint32x4 th = {hw_[0], hw_[1], hw_[2], hw_[3]};
        *(uint32x4*)(EH + (size_t)g * 1024 + (kg * 16 + rl) * 16) = th;
    }
}

// Partial projection: block (pb, ds) sums d in [ds*128, +128) for 256 pixels.
__global__ __launch_bounds__(256) void proj_partial(const float* __restrict__ enc, const float* __restrict__ pwT,
                                                    float* __restrict__ part) {
    __shared__ float lds[128 * FF];
    int pb = blockIdx.x, ds = blockIdx.y;
    int d0 = ds * 128;
    for (int i = threadIdx.x; i < 128 * FF; i += 256) lds[i] = pwT[d0 * FF + i];
    __syncthreads();
    int p = pb * 256 + threadIdx.x;
    int b = p >> 10, hw = p & 1023;
    const float* ep = enc + (size_t)b * DD * HWS + hw;
    float acc[FF];
#pragma unroll
    for (int f = 0; f < FF; f++) acc[f] = 0.f;
    for (int dl = 0; dl < 128; dl++) {
        float ev = ep[(size_t)(d0 + dl) * HWS];
        const float4* w4 = (const float4*)&lds[dl * FF];
#pragma unroll
        for (int q = 0; q < 8; q++) {
            float4 w = w4[q];
            acc[q * 4 + 0] = fmaf(ev, w.x, acc[q * 4 + 0]);
            acc[q * 4 + 1] = fmaf(ev, w.y, acc[q * 4 + 1]);
            acc[q * 4 + 2] = fmaf(ev, w.z, acc[q * 4 + 2]);
            acc[q * 4 + 3] = fmaf(ev, w.w, acc[q * 4 + 3]);
        }
    }
    float4* o = (float4*)(part + ((size_t)ds * NPIX + p) * FF);
#pragma unroll
    for (int q = 0; q < 8; q++)
        o[q] = make_float4(acc[q * 4], acc[q * 4 + 1], acc[q * 4 + 2], acc[q * 4 + 3]);
}

// Sum partials + bias, l2norm -> X fp32 + bf16-h fragments XH ([p][kg] 16B pieces)
__global__ __launch_bounds__(256) void finish_x(const float* __restrict__ part, const float* __restrict__ pbias,
                                                float* __restrict__ X, char* __restrict__ XH) {
    int p = blockIdx.x * 256 + threadIdx.x;
    float acc[FF];
#pragma unroll
    for (int f = 0; f < FF; f++) acc[f] = 0.f;
    for (int sg = 0; sg < DSPLIT; sg++) {
        const float4* r = (const float4*)(part + ((size_t)sg * NPIX + p) * FF);
#pragma unroll
        for (int q = 0; q < 8; q++) {
            float4 v = r[q];
            acc[q * 4 + 0] += v.x; acc[q * 4 + 1] += v.y;
            acc[q * 4 + 2] += v.z; acc[q * 4 + 3] += v.w;
        }
    }
#pragma unroll
    for (int f = 0; f < FF; f++) acc[f] += pbias[f];
    float s = 0.f;
#pragma unroll
    for (int f = 0; f < FF; f++) s += acc[f] * acc[f];
    float m = fmaxf(sqrtf(s), 1e-6f);
#pragma unroll
    for (int f = 0; f < FF; f++) acc[f] = acc[f] / m;
    float4* o = (float4*)(X + (size_t)p * FF);
#pragma unroll
    for (int q = 0; q < 8; q++)
        o[q] = make_float4(acc[q * 4], acc[q * 4 + 1], acc[q * 4 + 2], acc[q * 4 + 3]);
#pragma unroll
    for (int kg = 0; kg < 4; kg++) {
        unsigned hw_[4];
#pragma unroll
        for (int w = 0; w < 4; w++) {
            unsigned short h0 = bf16_rne(acc[kg * 8 + w * 2]);
            unsigned short h1 = bf16_rne(acc[kg * 8 + w * 2 + 1]);
            hw_[w] = (unsigned)h0 | ((unsigned)h1 << 16);
        }
        uint32x4 th = {hw_[0], hw_[1], hw_[2], hw_[3]};
        *(uint32x4*)(XH + (size_t)p * 64 + kg * 16) = th;
    }
}

// Phase 1: approx sims (h.h only), per-pixel MAX VALUE -> keys32 (monotonic u32 atomicMax).
// Barrier-free, LDS-free: B tiles stream from global, 4-deep register prefetch.
// Wave = 64 pixels (4 A-tiles). grid (32 m, 16 n), 256 threads.
#define APPROX_TILE(S)                                          \
    {                                                           \
        bf16x8 bh = __builtin_bit_cast(bf16x8, S);              \
        f32x4 c0 = {0.f,0.f,0.f,0.f}, c1 = {0.f,0.f,0.f,0.f};   \
        f32x4 c2 = {0.f,0.f,0.f,0.f}, c3 = {0.f,0.f,0.f,0.f};   \
        c0 = mfma16(ah[0], bh, c0); c1 = mfma16(ah[1], bh, c1); \
        c2 = mfma16(ah[2], bh, c2); c3 = mfma16(ah[3], bh, c3); \
        _Pragma("unroll")                                       \
        for (int i = 0; i < 4; i++) {                           \
            bv[i]      = fmaxf(bv[i],      c0[i]);              \
            bv[4 + i]  = fmaxf(bv[4 + i],  c1[i]);              \
            bv[8 + i]  = fmaxf(bv[8 + i],  c2[i]);              \
            bv[12 + i] = fmaxf(bv[12 + i], c3[i]);              \
        }                                                       \
    }

__global__ __launch_bounds__(256) void argmax_approx(const uint32x4* __restrict__ XHp,
                                                     const char* __restrict__ EH,
                                                     unsigned* __restrict__ keys32) {
    int tid = threadIdx.x, lane = tid & 63, wv = tid >> 6;
    int rl = lane & 15, kg = lane >> 4;
    int wavebase = blockIdx.x * 256 + wv * 64;
    int nblk = blockIdx.y;
    bf16x8 ah[4];
#pragma unroll
    for (int m = 0; m < 4; m++)
        ah[m] = __builtin_bit_cast(bf16x8, XHp[(wavebase + m * 16 + rl) * 4 + kg]);
    const char* pb = EH + (size_t)nblk * 65536 + lane * 16;
    float bv[16];
#pragma unroll
    for (int j = 0; j < 16; j++) bv[j] = -3.0e38f;

    uint32x4 s0 = *(const uint32x4*)(pb);
    uint32x4 s1 = *(const uint32x4*)(pb + 1024);
    uint32x4 s2 = *(const uint32x4*)(pb + 2048);
    uint32x4 s3 = *(const uint32x4*)(pb + 3072);
    for (int t = 0; t < 64; t += 2) {
        uint32x4 n0 = *(const uint32x4*)(pb + (t + 4) * 1024);   // overreads <=4KB past EH: harmless
        uint32x4 n1 = *(const uint32x4*)(pb + (t + 5) * 1024);
        APPROX_TILE(s0)
        APPROX_TILE(s1)
        s0 = s2; s1 = s3; s2 = n0; s3 = n1;
    }
    // max over the 16 code-columns (rl) within each kg group
#pragma unroll
    for (int st = 1; st < 16; st <<= 1)
#pragma unroll
        for (int j = 0; j < 16; j++) bv[j] = fmaxf(bv[j], __shfl_xor(bv[j], st));
    if (rl == 0) {
#pragma unroll
        for (int j = 0; j < 16; j++)
            atomicMax(keys32 + wavebase + (j >> 2) * 16 + kg * 4 + (j & 3), mono_u32(bv[j]));
    }
}

// Phase 2: recompute identical approx sims; candidates (approx >= pixelmax - MARGIN)
// get an exact fp32 dot (X . EN) and a packed-key atomicMax into keys64.
#define EXACT_TILE(S, T)                                                          \
    {                                                                             \
        bf16x8 bh = __builtin_bit_cast(bf16x8, S);                                \
        f32x4 c0 = {0.f,0.f,0.f,0.f}, c1 = {0.f,0.f,0.f,0.f};                     \
        f32x4 c2 = {0.f,0.f,0.f,0.f}, c3 = {0.f,0.f,0.f,0.f};                     \
        c0 = mfma16(ah[0], bh, c0); c1 = mfma16(ah[1], bh, c1);                   \
        c2 = mfma16(ah[2], bh, c2); c3 = mfma16(ah[3], bh, c3);                   \
        float dm = c0[0] - thr[0];                                                \
        _Pragma("unroll")                                                         \
        for (int i = 0; i < 4; i++) {                                             \
            dm = fmaxf(dm, c0[i] - thr[i]);                                       \
            dm = fmaxf(dm, c1[i] - thr[4 + i]);                                   \
            dm = fmaxf(dm, c2[i] - thr[8 + i]);                                   \
            dm = fmaxf(dm, c3[i] - thr[12 + i]);                                  \
        }                                                                         \
        if (dm >= 0.f) {                                                          \
            float av[16];                                                         \
            _Pragma("unroll")                                                     \
            for (int i = 0; i < 4; i++) {                                         \
                av[i] = c0[i]; av[4 + i] = c1[i];                                 \
                av[8 + i] = c2[i]; av[12 + i] = c3[i];                            \
            }                                                                     \
            _Pragma("unroll")                                                     \
            for (int j = 0; j < 16; j++) {                                        \
                if (av[j] >= thr[j]) {                                            \
                    int p = wavebase + (j >> 2) * 16 + kg * 4 + (j & 3);          \
                    int n = nblk * 1024 + (T) * 16 + rl;                          \
                    const float4* xr = (const float4*)(X + (size_t)p * FF);       \
                    const float4* er = (const float4*)(EN + (size_t)n * FF);      \
                    float a0 = 0.f, a1 = 0.f, a2 = 0.f, a3 = 0.f;                 \
                    _Pragma("unroll")                                             \
                    for (int q = 0; q < 8; q++) {                                 \
                        float4 xv = xr[q], ev = er[q];                            \
                        a0 = fmaf(xv.x, ev.x, a0); a1 = fmaf(xv.y, ev.y, a1);     \
                        a2 = fmaf(xv.z, ev.z, a2); a3 = fmaf(xv.w, ev.w, a3);     \
                    }                                                             \
                    float v = (a0 + a1) + (a2 + a3);                              \
                    atomicMax(keys64 + p, packkey(v, n));                         \
                }                                                                 \
            }                                                                     \
        }                                                                         \
    }

__global__ __launch_bounds__(256) void argmax_exact(const uint32x4* __restrict__ XHp,
                                                    const char* __restrict__ EH,
                                                    const unsigned* __restrict__ keys32,
                                                    const float* __restrict__ X, const float* __restrict__ EN,
                                                    unsigned long long* __restrict__ keys64) {
    int tid = threadIdx.x, lane = tid & 63, wv = tid >> 6;
    int rl = lane & 15, kg = lane >> 4;
    int wavebase = blockIdx.x * 256 + wv * 64;
    int nblk = blockIdx.y;
    bf16x8 ah[4];
#pragma unroll
    for (int m = 0; m < 4; m++)
        ah[m] = __builtin_bit_cast(bf16x8, XHp[(wavebase + m * 16 + rl) * 4 + kg]);
    float thr[16];
#pragma unroll
    for (int j = 0; j < 16; j++)
        thr[j] = mono_dec(keys32[wavebase + (j >> 2) * 16 + kg * 4 + (j & 3)]) - MARGIN;
    const char* pb = EH + (size_t)nblk * 65536 + lane * 16;

    uint32x4 s0 = *(const uint32x4*)(pb);
    uint32x4 s1 = *(const uint32x4*)(pb + 1024);
    uint32x4 s2 = *(const uint32x4*)(pb + 2048);
    uint32x4 s3 = *(const uint32x4*)(pb + 3072);
    for (int t = 0; t < 64; t += 2) {
        uint32x4 n0 = *(const uint32x4*)(pb + (t + 4) * 1024);
        uint32x4 n1 = *(const uint32x4*)(pb + (t + 5) * 1024);
        EXACT_TILE(s0, t)
        EXACT_TILE(s1, t + 1)
        s0 = s2; s1 = s3; s2 = n0; s3 = n1;
    }
}

// out[b,d,hw] = sum_f lat[f]*exp_w[d,f] + exp_b[d]. Wave wv==0 of y==0 also does
// closest/hist/loss (it already has n and lat).
__global__ __launch_bounds__(256) void expand_out(const unsigned long long* __restrict__ keys64,
                                                  const float* __restrict__ EN, const float* __restrict__ ew,
                                                  const float* __restrict__ eb, const float* __restrict__ X,
                                                  float* __restrict__ out, float* __restrict__ closest_out,
                                                  int* __restrict__ counts, float* __restrict__ misc) {
    int lane = threadIdx.x & 63, wv = threadIdx.x >> 6;
    int p = blockIdx.x * 64 + lane;
    unsigned n = ~(unsigned)(keys64[p]);
    float lat[FF];
    const float4* l4 = (const float4*)(EN + (size_t)n * FF);
#pragma unroll
    for (int q = 0; q < 8; q++) {
        float4 v = l4[q];
        lat[q * 4] = v.x; lat[q * 4 + 1] = v.y; lat[q * 4 + 2] = v.z; lat[q * 4 + 3] = v.w;
    }
    if (blockIdx.y == 0 && wv == 0) {
        closest_out[p] = (float)n;
        atomicAdd(counts + n, 1);
        const float4* xr = (const float4*)(X + (size_t)p * FF);
        float s = 0.f;
#pragma unroll
        for (int q = 0; q < 8; q++) {
            float4 xv = xr[q];
            float dx = xv.x - lat[q * 4], dy = xv.y - lat[q * 4 + 1];
            float dz = xv.z - lat[q * 4 + 2], dw = xv.w - lat[q * 4 + 3];
            s += dx * dx + dy * dy + dz * dz + dw * dw;
        }
        for (int off = 32; off > 0; off >>= 1) s += __shfl_down(s, off);
        if (lane == 0) atomicAdd(misc, s);
    }
    int b = p >> 10, hw = p & 1023;
    float* op = out + (size_t)b * DD * HWS + hw;
    int d0 = blockIdx.y * 64 + wv * 16;
    for (int i = 0; i < 16; i++) {
        int d = d0 + i;
        const float4* w4 = (const float4*)(ew + (size_t)d * FF);
        float4 w0 = w4[0], w1 = w4[1], w2 = w4[2], w3 = w4[3];
        float4 w5 = w4[4], w6 = w4[5], w7 = w4[6], w8 = w4[7];
        float a0 = fmaf(lat[0], w0.x, eb[d]);
        float a1 = lat[1] * w0.y;
        float a2 = lat[2] * w0.z;
        float a3 = lat[3] * w0.w;
        a0 = fmaf(lat[4],  w1.x, a0); a1 = fmaf(lat[5],  w1.y, a1); a2 = fmaf(lat[6],  w1.z, a2); a3 = fmaf(lat[7],  w1.w, a3);
        a0 = fmaf(lat[8],  w2.x, a0); a1 = fmaf(lat[9],  w2.y, a1); a2 = fmaf(lat[10], w2.z, a2); a3 = fmaf(lat[11], w2.w, a3);
        a0 = fmaf(lat[12], w3.x, a0); a1 = fmaf(lat[13], w3.y, a1); a2 = fmaf(lat[14], w3.z, a2); a3 = fmaf(lat[15], w3.w, a3);
        a0 = fmaf(lat[16], w5.x, a0); a1 = fmaf(lat[17], w5.y, a1); a2 = fmaf(lat[18], w5.z, a2); a3 = fmaf(lat[19], w5.w, a3);
        a0 = fmaf(lat[20], w6.x, a0); a1 = fmaf(lat[21], w6.y, a1); a2 = fmaf(lat[22], w6.z, a2); a3 = fmaf(lat[23], w6.w, a3);
        a0 = fmaf(lat[24], w7.x, a0); a1 = fmaf(lat[25], w7.y, a1); a2 = fmaf(lat[26], w7.z, a2); a3 = fmaf(lat[27], w7.w, a3);
        a0 = fmaf(lat[28], w8.x, a0); a1 = fmaf(lat[29], w8.y, a1); a2 = fmaf(lat[30], w8.z, a2); a3 = fmaf(lat[31], w8.w, a3);
        op[(size_t)d * HWS] = (a0 + a1) + (a2 + a3);
    }
}

__global__ __launch_bounds__(1024) void perp_final(const int* __restrict__ counts,
                                                   const float* __restrict__ misc, float* __restrict__ o) {
    __shared__ float red[16];
    float s = 0.f;
#pragma unroll
    for (int r = 0; r < 16; r++) {
        float u = (float)counts[threadIdx.x + r * 1024] * (1.0f / 8192.0f);
        s += u * logf(u + 1e-6f);
    }
    for (int off = 32; off > 0; off >>= 1) s += __shfl_down(s, off);
    if ((threadIdx.x & 63) == 0) red[threadIdx.x >> 6] = s;
    __syncthreads();
    if (threadIdx.x == 0) {
        float t = 0.f;
        for (int i = 0; i < 16; i++) t += red[i];
        o[0] = misc[0] * (1.0f / 262144.0f);   // mean over B*F*H*W
        o[1] = expf(-t);
    }
}

extern "C" void kernel_launch(void* const* d_in, const int* in_sizes, int n_in,
                              void* d_out, int out_size, void* d_ws, size_t ws_size,
                              hipStream_t stream) {
    const float* enc = (const float*)d_in[0];
    const float* emb = (const float*)d_in[1];
    const float* pw  = (const float*)d_in[2];
    const float* pb  = (const float*)d_in[3];
    const float* ew  = (const float*)d_in[4];
    const float* eb  = (const float*)d_in[5];
    float* out = (float*)d_out;
    char* ws = (char*)d_ws;

    unsigned long long* keys64 = (unsigned long long*)(ws + WS_KEYS64);
    unsigned* keys32 = (unsigned*)(ws + WS_KEYS32);
    int*   counts = (int*)(ws + WS_COUNTS);
    float* misc   = (float*)(ws + WS_MISC);
    float* pwT    = (float*)(ws + WS_PWT);
    float* EN     = (float*)(ws + WS_EN);
    char*  EH     = ws + WS_EH;
    float* X      = (float*)(ws + WS_X);
    char*  XH     = ws + WS_XH;
    float* part   = (float*)(ws + WS_PART);

    prep<<<64, 256, 0, stream>>>(pw, emb, pwT, EN, EH, keys64, keys32, counts, misc);
    proj_partial<<<dim3(32, DSPLIT), 256, 0, stream>>>(enc, pwT, part);
    finish_x<<<32, 256, 0, stream>>>(part, pb, X, XH);
    argmax_approx<<<dim3(32, 16), 256, 0, stream>>>((const uint32x4*)XH, EH, keys32);
    argmax_exact<<<dim3(32, 16), 256, 0, stream>>>((const uint32x4*)XH, EH, keys32, X, EN, keys64);
    expand_out<<<dim3(128, 8), 256, 0, stream>>>(keys64, EN, ew, eb, X, out, out + 4194304, counts, misc);
    perp_final<<<1, 1024, 0, stream>>>(counts, misc, out + 4194304 + NPIX);
}

// Round 4
// 92.281 us; speedup vs baseline: 2.1687x; 1.2665x over previous
//
#include <hip/hip_runtime.h>
#include <math.h>

#define NPIX 8192
#define DD 512
#define FF 32
#define NN 16384
#define HWS 1024
#define DSPLIT 16
#define MARGIN 0.012f

// ws layout (bytes); ws_size ~256MB (harness poison fills show 262144 KB)
#define WS_KEYS64 0         // 8192*8  = 65536
#define WS_KEYS32 65536     // 8192*4  = 32768
#define WS_COUNTS 98304     // 16384*4 = 65536
#define WS_MISC   163840    // 256 (loss accumulator)
#define WS_EN     229632    // 2 MB
#define WS_EH     2326784   // 1 MB (tile-major bf16 h-split; overread spills into WS_X: harmless)
#define WS_X      3375360   // 1 MB
#define WS_XH     4423936   // 512 KB
#define WS_PART   4948224   // 16*8192*32*4 = 16 MB (end ~21.7 MB)

typedef __bf16 bf16x8 __attribute__((ext_vector_type(8)));
typedef float f32x4 __attribute__((ext_vector_type(4)));
typedef unsigned int uint32x4 __attribute__((ext_vector_type(4)));

__device__ __forceinline__ unsigned short bf16_rne(float f) {
    unsigned u = __float_as_uint(f);
    u += 0x7fffu + ((u >> 16) & 1u);
    return (unsigned short)(u >> 16);
}
__device__ __forceinline__ f32x4 mfma16(bf16x8 a, bf16x8 b, f32x4 c) {
    return __builtin_amdgcn_mfma_f32_16x16x32_bf16(a, b, c, 0, 0, 0);
}
__device__ __forceinline__ unsigned mono_u32(float v) {
    unsigned u = __float_as_uint(v);
    return (u & 0x80000000u) ? ~u : (u | 0x80000000u);
}
__device__ __forceinline__ float mono_dec(unsigned u) {
    return __uint_as_float((u & 0x80000000u) ? (u ^ 0x80000000u) : ~u);
}
__device__ __forceinline__ unsigned long long packkey(float v, int n) {
    return ((unsigned long long)mono_u32(v) << 32) | (unsigned long long)(~(unsigned)n);
}

// Fused: blocks 0..511 = partial projection (pb = bx&31, ds = bx>>5, 32 d each);
// blocks 512..575 = codebook l2-norm (EN fp32 + EH bf16-h tile-major) + zero-init.
__global__ __launch_bounds__(256) void prep_proj(const float* __restrict__ pw, const float* __restrict__ emb,
                                                 const float* __restrict__ enc, float* __restrict__ part,
                                                 float* __restrict__ EN, char* __restrict__ EH,
                                                 unsigned long long* __restrict__ keys64,
                                                 unsigned* __restrict__ keys32, int* __restrict__ counts,
                                                 float* __restrict__ misc) {
    int bx = blockIdx.x;
    if (bx < 512) {
        __shared__ float lds[32 * FF];
        int pb = bx & 31, ds = bx >> 5;
        int d0 = ds * 32;
        for (int i = threadIdx.x; i < 32 * FF; i += 256) {
            int dl = i >> 5, f = i & 31;
            lds[dl * FF + f] = pw[f * DD + d0 + dl];   // transpose folded into stage
        }
        __syncthreads();
        int p = pb * 256 + threadIdx.x;
        int b = p >> 10, hw = p & 1023;
        const float* ep = enc + (size_t)b * DD * HWS + (size_t)d0 * HWS + hw;
        float acc[FF];
#pragma unroll
        for (int f = 0; f < FF; f++) acc[f] = 0.f;
        float ev[4];
#pragma unroll
        for (int j = 0; j < 4; j++) ev[j] = ep[(size_t)j * HWS];
#pragma unroll
        for (int g = 0; g < 8; g++) {
            float nv[4];
            if (g < 7) {
#pragma unroll
                for (int j = 0; j < 4; j++) nv[j] = ep[(size_t)(g * 4 + 4 + j) * HWS];
            }
#pragma unroll
            for (int j = 0; j < 4; j++) {
                const float4* w4 = (const float4*)&lds[(g * 4 + j) * FF];
#pragma unroll
                for (int q = 0; q < 8; q++) {
                    float4 w = w4[q];
                    acc[q * 4 + 0] = fmaf(ev[j], w.x, acc[q * 4 + 0]);
                    acc[q * 4 + 1] = fmaf(ev[j], w.y, acc[q * 4 + 1]);
                    acc[q * 4 + 2] = fmaf(ev[j], w.z, acc[q * 4 + 2]);
                    acc[q * 4 + 3] = fmaf(ev[j], w.w, acc[q * 4 + 3]);
                }
            }
            if (g < 7) {
#pragma unroll
                for (int j = 0; j < 4; j++) ev[j] = nv[j];
            }
        }
        float4* o = (float4*)(part + ((size_t)ds * NPIX + p) * FF);
#pragma unroll
        for (int q = 0; q < 8; q++)
            o[q] = make_float4(acc[q * 4], acc[q * 4 + 1], acc[q * 4 + 2], acc[q * 4 + 3]);
    } else {
        int i = (bx - 512) * 256 + threadIdx.x;   // 0..16383
        counts[i] = 0;
        if (i < 8192) { keys64[i] = 0ull; keys32[i] = 0u; }
        if (i < 8) misc[i] = 0.f;
        const float4* r = (const float4*)(emb + (size_t)i * FF);
        float e[FF];
        float s = 0.f;
#pragma unroll
        for (int q = 0; q < 8; q++) {
            float4 v = r[q];
            e[q * 4] = v.x; e[q * 4 + 1] = v.y; e[q * 4 + 2] = v.z; e[q * 4 + 3] = v.w;
            s += v.x * v.x + v.y * v.y + v.z * v.z + v.w * v.w;
        }
        float m = fmaxf(sqrtf(s), 1e-6f);
#pragma unroll
        for (int f = 0; f < FF; f++) e[f] = e[f] / m;
        float4* o = (float4*)(EN + (size_t)i * FF);
#pragma unroll
        for (int q = 0; q < 8; q++)
            o[q] = make_float4(e[q * 4], e[q * 4 + 1], e[q * 4 + 2], e[q * 4 + 3]);
        int g = i >> 4, rl = i & 15;
#pragma unroll
        for (int kg = 0; kg < 4; kg++) {
            unsigned hw_[4];
#pragma unroll
            for (int w = 0; w < 4; w++) {
                unsigned short h0 = bf16_rne(e[kg * 8 + w * 2]);
                unsigned short h1 = bf16_rne(e[kg * 8 + w * 2 + 1]);
                hw_[w] = (unsigned)h0 | ((unsigned)h1 << 16);
            }
            uint32x4 th = {hw_[0], hw_[1], hw_[2], hw_[3]};
            *(uint32x4*)(EH + (size_t)g * 1024 + (kg * 16 + rl) * 16) = th;
        }
    }
}

// Sum partials + bias, l2norm -> X fp32 + bf16-h XH. 4 threads/pixel (8 ch each).
__global__ __launch_bounds__(256) void finish_x(const float* __restrict__ part, const float* __restrict__ pbias,
                                                float* __restrict__ X, char* __restrict__ XH) {
    int t = blockIdx.x * 256 + threadIdx.x;
    int p = t >> 2, q = t & 3;
    float a8[8];
#pragma unroll
    for (int j = 0; j < 8; j++) a8[j] = 0.f;
    for (int sg = 0; sg < DSPLIT; sg++) {
        const float4* r = (const float4*)(part + ((size_t)sg * NPIX + p) * FF + q * 8);
        float4 v0 = r[0], v1 = r[1];
        a8[0] += v0.x; a8[1] += v0.y; a8[2] += v0.z; a8[3] += v0.w;
        a8[4] += v1.x; a8[5] += v1.y; a8[6] += v1.z; a8[7] += v1.w;
    }
#pragma unroll
    for (int j = 0; j < 8; j++) a8[j] += pbias[q * 8 + j];
    float ss = 0.f;
#pragma unroll
    for (int j = 0; j < 8; j++) ss += a8[j] * a8[j];
    ss += __shfl_xor(ss, 1);
    ss += __shfl_xor(ss, 2);
    float m = fmaxf(sqrtf(ss), 1e-6f);
#pragma unroll
    for (int j = 0; j < 8; j++) a8[j] = a8[j] / m;
    float4* o = (float4*)(X + (size_t)p * FF + q * 8);
    o[0] = make_float4(a8[0], a8[1], a8[2], a8[3]);
    o[1] = make_float4(a8[4], a8[5], a8[6], a8[7]);
    unsigned hw_[4];
#pragma unroll
    for (int w = 0; w < 4; w++) {
        unsigned short h0 = bf16_rne(a8[w * 2]);
        unsigned short h1 = bf16_rne(a8[w * 2 + 1]);
        hw_[w] = (unsigned)h0 | ((unsigned)h1 << 16);
    }
    uint32x4 th = {hw_[0], hw_[1], hw_[2], hw_[3]};
    *(uint32x4*)(XH + (size_t)p * 64 + q * 16) = th;
}

// Phase 1: approx sims (h.h only) -> per-pixel max value via u32 atomicMax.
// Barrier-free, LDS-free; B tiles stream from global with 4-deep prefetch.
#define APPROX_TILE(S)                                          \
    {                                                           \
        bf16x8 bh = __builtin_bit_cast(bf16x8, S);              \
        f32x4 c0 = {0.f,0.f,0.f,0.f}, c1 = {0.f,0.f,0.f,0.f};   \
        f32x4 c2 = {0.f,0.f,0.f,0.f}, c3 = {0.f,0.f,0.f,0.f};   \
        c0 = mfma16(ah[0], bh, c0); c1 = mfma16(ah[1], bh, c1); \
        c2 = mfma16(ah[2], bh, c2); c3 = mfma16(ah[3], bh, c3); \
        _Pragma("unroll")                                       \
        for (int i = 0; i < 4; i++) {                           \
            bv[i]      = fmaxf(bv[i],      c0[i]);              \
            bv[4 + i]  = fmaxf(bv[4 + i],  c1[i]);              \
            bv[8 + i]  = fmaxf(bv[8 + i],  c2[i]);              \
            bv[12 + i] = fmaxf(bv[12 + i], c3[i]);              \
        }                                                       \
    }

__global__ __launch_bounds__(256) void argmax_approx(const uint32x4* __restrict__ XHp,
                                                     const char* __restrict__ EH,
                                                     unsigned* __restrict__ keys32) {
    int tid = threadIdx.x, lane = tid & 63, wv = tid >> 6;
    int rl = lane & 15, kg = lane >> 4;
    int wavebase = blockIdx.x * 256 + wv * 64;
    int nblk = blockIdx.y;
    bf16x8 ah[4];
#pragma unroll
    for (int m = 0; m < 4; m++)
        ah[m] = __builtin_bit_cast(bf16x8, XHp[(wavebase + m * 16 + rl) * 4 + kg]);
    const char* pb = EH + (size_t)nblk * 32768 + lane * 16;
    float bv[16];
#pragma unroll
    for (int j = 0; j < 16; j++) bv[j] = -3.0e38f;

    uint32x4 s0 = *(const uint32x4*)(pb);
    uint32x4 s1 = *(const uint32x4*)(pb + 1024);
    uint32x4 s2 = *(const uint32x4*)(pb + 2048);
    uint32x4 s3 = *(const uint32x4*)(pb + 3072);
    for (int t = 0; t < 32; t += 2) {
        uint32x4 n0 = *(const uint32x4*)(pb + (t + 4) * 1024);   // overread <=4KB: harmless
        uint32x4 n1 = *(const uint32x4*)(pb + (t + 5) * 1024);
        APPROX_TILE(s0)
        APPROX_TILE(s1)
        s0 = s2; s1 = s3; s2 = n0; s3 = n1;
    }
#pragma unroll
    for (int st = 1; st < 16; st <<= 1)
#pragma unroll
        for (int j = 0; j < 16; j++) bv[j] = fmaxf(bv[j], __shfl_xor(bv[j], st));
    if (rl == 0) {
#pragma unroll
        for (int j = 0; j < 16; j++)
            atomicMax(keys32 + wavebase + (j >> 2) * 16 + kg * 4 + (j & 3), mono_u32(bv[j]));
    }
}

// Phase 2: recompute approx; candidates (>= pixelmax - MARGIN) get exact fp32 dot.
#define EXACT_TILE(S, T)                                                          \
    {                                                                             \
        bf16x8 bh = __builtin_bit_cast(bf16x8, S);                                \
        f32x4 c0 = {0.f,0.f,0.f,0.f}, c1 = {0.f,0.f,0.f,0.f};                     \
        f32x4 c2 = {0.f,0.f,0.f,0.f}, c3 = {0.f,0.f,0.f,0.f};                     \
        c0 = mfma16(ah[0], bh, c0); c1 = mfma16(ah[1], bh, c1);                   \
        c2 = mfma16(ah[2], bh, c2); c3 = mfma16(ah[3], bh, c3);                   \
        float dm = c0[0] - thr[0];                                                \
        _Pragma("unroll")                                                         \
        for (int i = 0; i < 4; i++) {                                             \
            dm = fmaxf(dm, c0[i] - thr[i]);                                       \
            dm = fmaxf(dm, c1[i] - thr[4 + i]);                                   \
            dm = fmaxf(dm, c2[i] - thr[8 + i]);                                   \
            dm = fmaxf(dm, c3[i] - thr[12 + i]);                                  \
        }                                                                         \
        if (dm >= 0.f) {                                                          \
            float av[16];                                                         \
            _Pragma("unroll")                                                     \
            for (int i = 0; i < 4; i++) {                                         \
                av[i] = c0[i]; av[4 + i] = c1[i];                                 \
                av[8 + i] = c2[i]; av[12 + i] = c3[i];                            \
            }                                                                     \
            _Pragma("unroll")                                                     \
            for (int j = 0; j < 16; j++) {                                        \
                if (av[j] >= thr[j]) {                                            \
                    int p = wavebase + (j >> 2) * 16 + kg * 4 + (j & 3);          \
                    int n = nblk * 512 + (T) * 16 + rl;                           \
                    const float4* xr = (const float4*)(X + (size_t)p * FF);       \
                    const float4* er = (const float4*)(EN + (size_t)n * FF);      \
                    float a0 = 0.f, a1 = 0.f, a2 = 0.f, a3 = 0.f;                 \
                    _Pragma("unroll")                                             \
                    for (int q = 0; q < 8; q++) {                                 \
                        float4 xv = xr[q], ev = er[q];                            \
                        a0 = fmaf(xv.x, ev.x, a0); a1 = fmaf(xv.y, ev.y, a1);     \
                        a2 = fmaf(xv.z, ev.z, a2); a3 = fmaf(xv.w, ev.w, a3);     \
                    }                                                             \
                    float v = (a0 + a1) + (a2 + a3);                              \
                    atomicMax(keys64 + p, packkey(v, n));                         \
                }                                                                 \
            }                                                                     \
        }                                                                         \
    }

__global__ __launch_bounds__(256) void argmax_exact(const uint32x4* __restrict__ XHp,
                                                    const char* __restrict__ EH,
                                                    const unsigned* __restrict__ keys32,
                                                    const float* __restrict__ X, const float* __restrict__ EN,
                                                    unsigned long long* __restrict__ keys64) {
    int tid = threadIdx.x, lane = tid & 63, wv = tid >> 6;
    int rl = lane & 15, kg = lane >> 4;
    int wavebase = blockIdx.x * 256 + wv * 64;
    int nblk = blockIdx.y;
    bf16x8 ah[4];
#pragma unroll
    for (int m = 0; m < 4; m++)
        ah[m] = __builtin_bit_cast(bf16x8, XHp[(wavebase + m * 16 + rl) * 4 + kg]);
    float thr[16];
#pragma unroll
    for (int j = 0; j < 16; j++)
        thr[j] = mono_dec(keys32[wavebase + (j >> 2) * 16 + kg * 4 + (j & 3)]) - MARGIN;
    const char* pb = EH + (size_t)nblk * 32768 + lane * 16;

    uint32x4 s0 = *(const uint32x4*)(pb);
    uint32x4 s1 = *(const uint32x4*)(pb + 1024);
    uint32x4 s2 = *(const uint32x4*)(pb + 2048);
    uint32x4 s3 = *(const uint32x4*)(pb + 3072);
    for (int t = 0; t < 32; t += 2) {
        uint32x4 n0 = *(const uint32x4*)(pb + (t + 4) * 1024);
        uint32x4 n1 = *(const uint32x4*)(pb + (t + 5) * 1024);
        EXACT_TILE(s0, t)
        EXACT_TILE(s1, t + 1)
        s0 = s2; s1 = s3; s2 = n0; s3 = n1;
    }
}

// out[b,d,hw] = sum_f lat[f]*exp_w[d,f] + exp_b[d]; wave 0 of y==0 also does
// closest/hist/loss.
__global__ __launch_bounds__(256) void expand_out(const unsigned long long* __restrict__ keys64,
                                                  const float* __restrict__ EN, const float* __restrict__ ew,
                                                  const float* __restrict__ eb, const float* __restrict__ X,
                                                  float* __restrict__ out, float* __restrict__ closest_out,
                                                  int* __restrict__ counts, float* __restrict__ misc) {
    int lane = threadIdx.x & 63, wv = threadIdx.x >> 6;
    int p = blockIdx.x * 64 + lane;
    unsigned n = ~(unsigned)(keys64[p]);
    float lat[FF];
    const float4* l4 = (const float4*)(EN + (size_t)n * FF);
#pragma unroll
    for (int q = 0; q < 8; q++) {
        float4 v = l4[q];
        lat[q * 4] = v.x; lat[q * 4 + 1] = v.y; lat[q * 4 + 2] = v.z; lat[q * 4 + 3] = v.w;
    }
    if (blockIdx.y == 0 && wv == 0) {
        closest_out[p] = (float)n;
        atomicAdd(counts + n, 1);
        const float4* xr = (const float4*)(X + (size_t)p * FF);
        float s = 0.f;
#pragma unroll
        for (int q = 0; q < 8; q++) {
            float4 xv = xr[q];
            float dx = xv.x - lat[q * 4], dy = xv.y - lat[q * 4 + 1];
            float dz = xv.z - lat[q * 4 + 2], dw = xv.w - lat[q * 4 + 3];
            s += dx * dx + dy * dy + dz * dz + dw * dw;
        }
        for (int off = 32; off > 0; off >>= 1) s += __shfl_down(s, off);
        if (lane == 0) atomicAdd(misc, s);
    }
    int b = p >> 10, hw = p & 1023;
    float* op = out + (size_t)b * DD * HWS + hw;
    int d0 = blockIdx.y * 64 + wv * 16;
    for (int i = 0; i < 16; i++) {
        int d = d0 + i;
        const float4* w4 = (const float4*)(ew + (size_t)d * FF);
        float4 w0 = w4[0], w1 = w4[1], w2 = w4[2], w3 = w4[3];
        float4 w5 = w4[4], w6 = w4[5], w7 = w4[6], w8 = w4[7];
        float a0 = fmaf(lat[0], w0.x, eb[d]);
        float a1 = lat[1] * w0.y;
        float a2 = lat[2] * w0.z;
        float a3 = lat[3] * w0.w;
        a0 = fmaf(lat[4],  w1.x, a0); a1 = fmaf(lat[5],  w1.y, a1); a2 = fmaf(lat[6],  w1.z, a2); a3 = fmaf(lat[7],  w1.w, a3);
        a0 = fmaf(lat[8],  w2.x, a0); a1 = fmaf(lat[9],  w2.y, a1); a2 = fmaf(lat[10], w2.z, a2); a3 = fmaf(lat[11], w2.w, a3);
        a0 = fmaf(lat[12], w3.x, a0); a1 = fmaf(lat[13], w3.y, a1); a2 = fmaf(lat[14], w3.z, a2); a3 = fmaf(lat[15], w3.w, a3);
        a0 = fmaf(lat[16], w5.x, a0); a1 = fmaf(lat[17], w5.y, a1); a2 = fmaf(lat[18], w5.z, a2); a3 = fmaf(lat[19], w5.w, a3);
        a0 = fmaf(lat[20], w6.x, a0); a1 = fmaf(lat[21], w6.y, a1); a2 = fmaf(lat[22], w6.z, a2); a3 = fmaf(lat[23], w6.w, a3);
        a0 = fmaf(lat[24], w7.x, a0); a1 = fmaf(lat[25], w7.y, a1); a2 = fmaf(lat[26], w7.z, a2); a3 = fmaf(lat[27], w7.w, a3);
        a0 = fmaf(lat[28], w8.x, a0); a1 = fmaf(lat[29], w8.y, a1); a2 = fmaf(lat[30], w8.z, a2); a3 = fmaf(lat[31], w8.w, a3);
        op[(size_t)d * HWS] = (a0 + a1) + (a2 + a3);
    }
}

__global__ __launch_bounds__(1024) void perp_final(const int* __restrict__ counts,
                                                   const float* __restrict__ misc, float* __restrict__ o) {
    __shared__ float red[16];
    float s = 0.f;
#pragma unroll
    for (int r = 0; r < 16; r++) {
        float u = (float)counts[threadIdx.x + r * 1024] * (1.0f / 8192.0f);
        s += u * logf(u + 1e-6f);
    }
    for (int off = 32; off > 0; off >>= 1) s += __shfl_down(s, off);
    if ((threadIdx.x & 63) == 0) red[threadIdx.x >> 6] = s;
    __syncthreads();
    if (threadIdx.x == 0) {
        float t = 0.f;
        for (int i = 0; i < 16; i++) t += red[i];
        o[0] = misc[0] * (1.0f / 262144.0f);   // mean over B*F*H*W
        o[1] = expf(-t);
    }
}

extern "C" void kernel_launch(void* const* d_in, const int* in_sizes, int n_in,
                              void* d_out, int out_size, void* d_ws, size_t ws_size,
                              hipStream_t stream) {
    const float* enc = (const float*)d_in[0];
    const float* emb = (const float*)d_in[1];
    const float* pw  = (const float*)d_in[2];
    const float* pb  = (const float*)d_in[3];
    const float* ew  = (const float*)d_in[4];
    const float* eb  = (const float*)d_in[5];
    float* out = (float*)d_out;
    char* ws = (char*)d_ws;

    unsigned long long* keys64 = (unsigned long long*)(ws + WS_KEYS64);
    unsigned* keys32 = (unsigned*)(ws + WS_KEYS32);
    int*   counts = (int*)(ws + WS_COUNTS);
    float* misc   = (float*)(ws + WS_MISC);
    float* EN     = (float*)(ws + WS_EN);
    char*  EH     = ws + WS_EH;
    float* X      = (float*)(ws + WS_X);
    char*  XH     = ws + WS_XH;
    float* part   = (float*)(ws + WS_PART);

    prep_proj<<<576, 256, 0, stream>>>(pw, emb, enc, part, EN, EH, keys64, keys32, counts, misc);
    finish_x<<<128, 256, 0, stream>>>(part, pb, X, XH);
    argmax_approx<<<dim3(32, 32), 256, 0, stream>>>((const uint32x4*)XH, EH, keys32);
    argmax_exact<<<dim3(32, 32), 256, 0, stream>>>((const uint32x4*)XH, EH, keys32, X, EN, keys64);
    expand_out<<<dim3(128, 8), 256, 0, stream>>>(keys64, EN, ew, eb, X, out, out + 4194304, counts, misc);
    perp_final<<<1, 1024, 0, stream>>>(counts, misc, out + 4194304 + NPIX);
}